// Round 1
// baseline (4711.930 us; speedup 1.0000x reference)
//
#include <hip/hip_runtime.h>
#include <math.h>

#define NB 4
#define CIN 64
#define CIT 16
#define HH 128
#define WW 128
#define KS 7
#define PAD 3
#define HP 134          // 128 + 2*3
#define WPS 136         // padded row stride (134 rounded up, 16B-aligned rows)
#define L1 1024         // 32*32 query patches
#define DD 784          // 16*49
#define SCALE_F 10.0f

#define PLANE (CIT * HP * WPS)      // one batch's 16-channel padded tensor
#define SZPB (NB * PLANE)           // = 1166336 floats per tensor

__device__ __forceinline__ int voff_of(int d) {
    int c = d / 49, r = d % 49, i = r / 7, j = r % 7;
    return (c * HP + i) * WPS + j;
}

// K1: fused 1x1 convs (gamma->b1, theta->b2, phi->b3) into zero-padded planes.
__global__ __launch_bounds__(256) void k_prep(
    const float* __restrict__ bin,
    const float* __restrict__ gw, const float* __restrict__ gb,
    const float* __restrict__ tw, const float* __restrict__ tb,
    const float* __restrict__ pw, const float* __restrict__ pb,
    float* __restrict__ b1p, float* __restrict__ b2p, float* __restrict__ b3p)
{
    int p = blockIdx.x * 256 + threadIdx.x;
    if (p >= NB * HP * WPS) return;
    int x = p % WPS; int r = p / WPS; int y = r % HP; int bb = r / HP;
    bool inter = (x >= PAD && x < PAD + WW && y >= PAD && y < PAD + HH);
    float v[CIN];
    if (inter) {
        int iy = y - PAD, ix = x - PAD;
        const float* src = bin + ((size_t)(bb * CIN) * HH + iy) * WW + ix;
        #pragma unroll
        for (int ci = 0; ci < CIN; ++ci) v[ci] = src[ci * HH * WW];
    }
    int obase = bb * PLANE + y * WPS + x;
    for (int co = 0; co < CIT; ++co) {
        float a1 = 0.f, a2 = 0.f, a3 = 0.f;
        if (inter) {
            a1 = gb[co]; a2 = tb[co]; a3 = pb[co];
            #pragma unroll
            for (int ci = 0; ci < CIN; ++ci) {
                float vv = v[ci];
                a1 += gw[co * CIN + ci] * vv;
                a2 += tw[co * CIN + ci] * vv;
                a3 += pw[co * CIN + ci] * vv;
            }
        }
        b1p[obase + co * HP * WPS] = a1;
        b2p[obase + co * HP * WPS] = a2;
        b3p[obase + co * HP * WPS] = a3;
    }
}

// K2: one block per (batch, query). fp32 scores, online softmax, sparse PV.
__global__ __launch_bounds__(256) void k_attn(
    const float* __restrict__ b1p, const float* __restrict__ b2p,
    const float* __restrict__ b3p, float* __restrict__ Zp)
{
    int blk = blockIdx.x;
    int q = blk & (L1 - 1);
    int bb = blk >> 10;
    int qh = q >> 5, qw = q & 31;
    int qy = qh * 4, qx = qw * 4;
    int tid = threadIdx.x;
    int u = tid & 31, rit = tid >> 5;   // 32 threads/row, 8 key-rows per tile
    int kx0 = u * 4;                    // each thread: 4 consecutive kx

    __shared__ float redmax[4], redsum[4];
    __shared__ int qcnt;
    __shared__ float qwgt[1024];
    __shared__ int qkey[1024];

    const float* b1b = b1p + bb * PLANE;
    const float* b2b = b2p + bb * PLANE;
    const float* b3b = b3p + bb * PLANE;

    float acc0 = 0.f, acc1 = 0.f, acc2 = 0.f, acc3 = 0.f;
    float m = -INFINITY, l = 0.f;

    int off0 = voff_of(tid);
    int off1 = voff_of(tid + 256);
    int off2 = voff_of(tid + 512);
    int off3 = (tid < DD - 768) ? voff_of(tid + 768) : 0;

    for (int tile = 0; tile < 16; ++tile) {
        int ky = tile * 8 + rit;
        float s0 = 0.f, s1 = 0.f, s2 = 0.f, s3 = 0.f;
        for (int c = 0; c < CIT; ++c) {
            #pragma unroll
            for (int i = 0; i < KS; ++i) {
                const float* krow = b3b + (c * HP + ky + i) * WPS + kx0;
                float4 ra = *(const float4*)krow;
                float4 rb = *(const float4*)(krow + 4);
                float2 rc = *(const float2*)(krow + 8);
                const float* qrow = b1b + (c * HP + qy + i) * WPS + qx; // block-uniform -> s_load
                float r0=ra.x,r1=ra.y,r2=ra.z,r3=ra.w,r4=rb.x,r5=rb.y,r6=rb.z,r7=rb.w,r8=rc.x,r9=rc.y;
                float qv;
                qv = qrow[0]; s0 += qv*r0; s1 += qv*r1; s2 += qv*r2; s3 += qv*r3;
                qv = qrow[1]; s0 += qv*r1; s1 += qv*r2; s2 += qv*r3; s3 += qv*r4;
                qv = qrow[2]; s0 += qv*r2; s1 += qv*r3; s2 += qv*r4; s3 += qv*r5;
                qv = qrow[3]; s0 += qv*r3; s1 += qv*r4; s2 += qv*r5; s3 += qv*r6;
                qv = qrow[4]; s0 += qv*r4; s1 += qv*r5; s2 += qv*r6; s3 += qv*r7;
                qv = qrow[5]; s0 += qv*r5; s1 += qv*r6; s2 += qv*r7; s3 += qv*r8;
                qv = qrow[6]; s0 += qv*r6; s1 += qv*r7; s2 += qv*r8; s3 += qv*r9;
            }
        }
        // block-wide max of this tile's 1024 scores
        float lm = fmaxf(fmaxf(s0, s1), fmaxf(s2, s3));
        #pragma unroll
        for (int o = 32; o > 0; o >>= 1) lm = fmaxf(lm, __shfl_xor(lm, o));
        if ((tid & 63) == 0) redmax[tid >> 6] = lm;
        if (tid == 0) qcnt = 0;
        __syncthreads();  // (A)
        float tmax = fmaxf(fmaxf(redmax[0], redmax[1]), fmaxf(redmax[2], redmax[3]));
        float mnew = fmaxf(m, tmax);
        float w0 = __expf(SCALE_F * (s0 - mnew));
        float w1 = __expf(SCALE_F * (s1 - mnew));
        float w2 = __expf(SCALE_F * (s2 - mnew));
        float w3 = __expf(SCALE_F * (s3 - mnew));
        const float WEPS = 1e-9f;  // dropped keys: <=16384*1e-9 relative mass
        if (w0 > WEPS) { int pos = atomicAdd(&qcnt, 1); qwgt[pos] = w0; qkey[pos] = (ky << 7) + kx0 + 0; }
        if (w1 > WEPS) { int pos = atomicAdd(&qcnt, 1); qwgt[pos] = w1; qkey[pos] = (ky << 7) + kx0 + 1; }
        if (w2 > WEPS) { int pos = atomicAdd(&qcnt, 1); qwgt[pos] = w2; qkey[pos] = (ky << 7) + kx0 + 2; }
        if (w3 > WEPS) { int pos = atomicAdd(&qcnt, 1); qwgt[pos] = w3; qkey[pos] = (ky << 7) + kx0 + 3; }
        float wsum = w0 + w1 + w2 + w3;
        #pragma unroll
        for (int o = 32; o > 0; o >>= 1) wsum += __shfl_xor(wsum, o);
        if ((tid & 63) == 0) redsum[tid >> 6] = wsum;
        __syncthreads();  // (B): queue + sums complete
        float tsum = redsum[0] + redsum[1] + redsum[2] + redsum[3];
        float sc = __expf(SCALE_F * (m - mnew));   // expf(-inf)=0 handles first tile
        acc0 *= sc; acc1 *= sc; acc2 *= sc; acc3 *= sc;
        l = l * sc + tsum;
        m = mnew;
        int n = qcnt;
        for (int e = 0; e < n; ++e) {
            float wv = qwgt[e];
            int kk = qkey[e];
            const float* vb = b2b + (kk >> 7) * WPS + (kk & 127);
            acc0 += wv * vb[off0];
            acc1 += wv * vb[off1];
            acc2 += wv * vb[off2];
            if (tid < DD - 768) acc3 += wv * vb[off3];
        }
        __syncthreads();  // (C): protect queue/redbufs before next tile
    }
    float inv = 1.f / l;
    float* zb = Zp + (size_t)(bb * DD) * L1 + q;
    zb[(size_t)tid * L1] = acc0 * inv;
    zb[(size_t)(tid + 256) * L1] = acc1 * inv;
    zb[(size_t)(tid + 512) * L1] = acc2 * inv;
    if (tid < DD - 768) zb[(size_t)(tid + 768) * L1] = acc3 * inv;
}

// K3: fold (overlap-add gather) + divide by overlap count + 1x1 out conv + residual.
__global__ __launch_bounds__(256) void k_fold(
    const float* __restrict__ bin, const float* __restrict__ ow,
    const float* __restrict__ ob, const float* __restrict__ Zp,
    float* __restrict__ outp)
{
    int p = blockIdx.x * 256 + threadIdx.x;
    if (p >= NB * HH * WW) return;
    int ox = p % WW; int r = p / WW; int oy = r % HH; int bb = r / HH;
    int yp = oy + PAD, xp = ox + PAD;
    int qh0 = (yp - 3) >> 2, qh1 = min(31, yp >> 2);
    int qw0 = (xp - 3) >> 2, qw1 = min(31, xp >> 2);
    float cnt = (float)((qh1 - qh0 + 1) * (qw1 - qw0 + 1));
    float y16[CIT];
    for (int c = 0; c < CIT; ++c) {
        float s = 0.f;
        for (int qhh = qh0; qhh <= qh1; ++qhh) {
            int i = yp - 4 * qhh;
            for (int qww = qw0; qww <= qw1; ++qww) {
                int j = xp - 4 * qww;
                s += Zp[(size_t)(bb * DD + c * 49 + i * 7 + j) * L1 + qhh * 32 + qww];
            }
        }
        y16[c] = s / cnt;
    }
    size_t oidx = ((size_t)(bb * CIN) * HH + oy) * WW + ox;
    for (int co = 0; co < CIN; ++co) {
        float a = ob[co];
        #pragma unroll
        for (int c = 0; c < CIT; ++c) a += ow[co * CIT + c] * y16[c];
        outp[oidx + (size_t)co * HH * WW] = bin[oidx + (size_t)co * HH * WW] + a;
    }
}

extern "C" void kernel_launch(void* const* d_in, const int* in_sizes, int n_in,
                              void* d_out, int out_size, void* d_ws, size_t ws_size,
                              hipStream_t stream) {
    (void)in_sizes; (void)n_in; (void)out_size; (void)ws_size;
    const float* bin = (const float*)d_in[0];
    const float* gw  = (const float*)d_in[1];
    const float* gb  = (const float*)d_in[2];
    const float* tw  = (const float*)d_in[3];
    const float* tb  = (const float*)d_in[4];
    const float* pw  = (const float*)d_in[5];
    const float* pb  = (const float*)d_in[6];
    const float* ow  = (const float*)d_in[7];
    const float* ob  = (const float*)d_in[8];
    float* ws  = (float*)d_ws;
    float* b1p = ws;
    float* b2p = ws + SZPB;
    float* b3p = ws + 2 * (size_t)SZPB;
    float* Zp  = ws + 3 * (size_t)SZPB;   // [NB][DD][L1] fp32
    float* outp = (float*)d_out;

    hipLaunchKernelGGL(k_prep, dim3((NB * HP * WPS + 255) / 256), dim3(256), 0, stream,
                       bin, gw, gb, tw, tb, pw, pb, b1p, b2p, b3p);
    hipLaunchKernelGGL(k_attn, dim3(NB * L1), dim3(256), 0, stream,
                       b1p, b2p, b3p, Zp);
    hipLaunchKernelGGL(k_fold, dim3((NB * HH * WW + 255) / 256), dim3(256), 0, stream,
                       bin, ow, ob, Zp, outp);
}

// Round 2
// 1480.334 us; speedup vs baseline: 3.1830x; 3.1830x over previous
//
#include <hip/hip_runtime.h>
#include <math.h>

#define NB 4
#define CIN 64
#define CIT 16
#define HH 128
#define WW 128
#define KS 7
#define PAD 3
#define HP 134          // 128 + 2*3
#define WPS 136         // padded row stride (134 rounded up, 16B-aligned rows)
#define L1 1024         // 32*32 query patches
#define DD 784          // 16*49
#define SCALE_F 10.0f
#define QPB 4           // queries per block (along qw)
#define QCAP 256        // per-query per-tile candidate queue capacity

#define PLANE (CIT * HP * WPS)      // one batch's 16-channel padded tensor
#define SZPB (NB * PLANE)

__device__ __forceinline__ int voff_of(int d) {
    int c = d / 49, r = d % 49, i = r / 7, j = r % 7;
    return (c * HP + i) * WPS + j;
}

// K1: fused 1x1 convs (gamma->b1, theta->b2, phi->b3) into zero-padded planes.
__global__ __launch_bounds__(256) void k_prep(
    const float* __restrict__ bin,
    const float* __restrict__ gw, const float* __restrict__ gb,
    const float* __restrict__ tw, const float* __restrict__ tb,
    const float* __restrict__ pw, const float* __restrict__ pb,
    float* __restrict__ b1p, float* __restrict__ b2p, float* __restrict__ b3p)
{
    int p = blockIdx.x * 256 + threadIdx.x;
    if (p >= NB * HP * WPS) return;
    int x = p % WPS; int r = p / WPS; int y = r % HP; int bb = r / HP;
    bool inter = (x >= PAD && x < PAD + WW && y >= PAD && y < PAD + HH);
    float v[CIN];
    if (inter) {
        int iy = y - PAD, ix = x - PAD;
        const float* src = bin + ((size_t)(bb * CIN) * HH + iy) * WW + ix;
        #pragma unroll
        for (int ci = 0; ci < CIN; ++ci) v[ci] = src[ci * HH * WW];
    }
    int obase = bb * PLANE + y * WPS + x;
    for (int co = 0; co < CIT; ++co) {
        float a1 = 0.f, a2 = 0.f, a3 = 0.f;
        if (inter) {
            a1 = gb[co]; a2 = tb[co]; a3 = pb[co];
            #pragma unroll
            for (int ci = 0; ci < CIN; ++ci) {
                float vv = v[ci];
                a1 += gw[co * CIN + ci] * vv;
                a2 += tw[co * CIN + ci] * vv;
                a3 += pw[co * CIN + ci] * vv;
            }
        }
        b1p[obase + co * HP * WPS] = a1;
        b2p[obase + co * HP * WPS] = a2;
        b3p[obase + co * HP * WPS] = a3;
    }
}

// K2: one block per (batch, 4 adjacent queries along qw).
// fp32 scores, online softmax, sparse PV via per-query candidate queues.
__global__ __launch_bounds__(256, 4) void k_attn(
    const float* __restrict__ b1p, const float* __restrict__ b2p,
    const float* __restrict__ b3p, float* __restrict__ Zp)
{
    int blk = blockIdx.x;
    int bb = blk >> 8;              // 256 blocks per batch
    int r = blk & 255;
    int qh = r >> 3, qwg = r & 7;   // query row, query-group (of 4) along w
    int qw0 = qwg * 4;
    int qy = qh * 4, qx = qw0 * 4;
    int tid = threadIdx.x;
    int u = tid & 31, rit = tid >> 5;   // 32 threads/key-row, 8 key-rows per tile
    int kx0 = u * 4;                    // each thread: 4 consecutive kx

    __shared__ float qld[CIT * KS * 20];       // q values: [c][i][x], x=0..19 (19 used)
    __shared__ float redmax[QPB][4], redsum[QPB][4];
    __shared__ int   qcnt[QPB];
    __shared__ float qwgt[QPB][QCAP];
    __shared__ int   qkey[QPB][QCAP];

    const float* b1b = b1p + bb * PLANE;
    const float* b2b = b2p + bb * PLANE;
    const float* b3b = b3p + bb * PLANE;

    // stage Q (4 patches = 19 consecutive cols x 7 rows x 16 ch) into LDS
    for (int t = tid; t < CIT * KS * 20; t += 256) {
        int x = t % 20; int rr = t / 20; int i = rr % KS; int c = rr / KS;
        qld[t] = b1b[(c * HP + qy + i) * WPS + qx + x];   // x=19 in-bounds (padded row)
    }
    __syncthreads();

    float acc[QPB][4];
    float m[QPB], l[QPB], mn[QPB];
    #pragma unroll
    for (int qq = 0; qq < QPB; ++qq) {
        m[qq] = -INFINITY; l[qq] = 0.f;
        #pragma unroll
        for (int t = 0; t < 4; ++t) acc[qq][t] = 0.f;
    }

    int off0 = voff_of(tid);
    int off1 = voff_of(tid + 256);
    int off2 = voff_of(tid + 512);
    int off3 = (tid < DD - 768) ? voff_of(tid + 768) : 0;

    for (int tile = 0; tile < 16; ++tile) {
        int ky = tile * 8 + rit;
        float s[QPB][4];
        #pragma unroll
        for (int qq = 0; qq < QPB; ++qq)
            #pragma unroll
            for (int t = 0; t < 4; ++t) s[qq][t] = 0.f;

        for (int c = 0; c < CIT; ++c) {
            #pragma unroll
            for (int i = 0; i < KS; ++i) {
                const float* krow = b3b + (c * HP + ky + i) * WPS + kx0;
                float4 ra = *(const float4*)krow;
                float4 rb = *(const float4*)(krow + 4);
                float2 rc = *(const float2*)(krow + 8);
                float r_[10] = {ra.x, ra.y, ra.z, ra.w, rb.x, rb.y, rb.z, rb.w, rc.x, rc.y};
                const float* qp = qld + (c * KS + i) * 20;
                float4 qa = *(const float4*)qp;
                float4 qb = *(const float4*)(qp + 4);
                float4 qc = *(const float4*)(qp + 8);
                float4 qd = *(const float4*)(qp + 12);
                float4 qe = *(const float4*)(qp + 16);
                float qv_[20] = {qa.x, qa.y, qa.z, qa.w, qb.x, qb.y, qb.z, qb.w,
                                 qc.x, qc.y, qc.z, qc.w, qd.x, qd.y, qd.z, qd.w,
                                 qe.x, qe.y, qe.z, qe.w};
                #pragma unroll
                for (int qq = 0; qq < QPB; ++qq) {
                    #pragma unroll
                    for (int j = 0; j < KS; ++j) {
                        float qv = qv_[4 * qq + j];
                        s[qq][0] += qv * r_[j];
                        s[qq][1] += qv * r_[j + 1];
                        s[qq][2] += qv * r_[j + 2];
                        s[qq][3] += qv * r_[j + 3];
                    }
                }
            }
        }

        // per-query block-wide max of this tile's 1024 scores
        #pragma unroll
        for (int qq = 0; qq < QPB; ++qq) {
            float v = fmaxf(fmaxf(s[qq][0], s[qq][1]), fmaxf(s[qq][2], s[qq][3]));
            #pragma unroll
            for (int o = 32; o > 0; o >>= 1) v = fmaxf(v, __shfl_xor(v, o));
            if ((tid & 63) == 0) redmax[qq][tid >> 6] = v;
        }
        if (tid < QPB) qcnt[tid] = 0;
        __syncthreads();  // (A)

        const float WEPS = 1e-9f;
        #pragma unroll
        for (int qq = 0; qq < QPB; ++qq) {
            float tmax = fmaxf(fmaxf(redmax[qq][0], redmax[qq][1]),
                               fmaxf(redmax[qq][2], redmax[qq][3]));
            float mnew = fmaxf(m[qq], tmax);
            mn[qq] = mnew;
            float w0 = __expf(SCALE_F * (s[qq][0] - mnew));
            float w1 = __expf(SCALE_F * (s[qq][1] - mnew));
            float w2 = __expf(SCALE_F * (s[qq][2] - mnew));
            float w3 = __expf(SCALE_F * (s[qq][3] - mnew));
            if (w0 > WEPS) { int pos = atomicAdd(&qcnt[qq], 1); if (pos < QCAP) { qwgt[qq][pos] = w0; qkey[qq][pos] = (ky << 7) + kx0 + 0; } }
            if (w1 > WEPS) { int pos = atomicAdd(&qcnt[qq], 1); if (pos < QCAP) { qwgt[qq][pos] = w1; qkey[qq][pos] = (ky << 7) + kx0 + 1; } }
            if (w2 > WEPS) { int pos = atomicAdd(&qcnt[qq], 1); if (pos < QCAP) { qwgt[qq][pos] = w2; qkey[qq][pos] = (ky << 7) + kx0 + 2; } }
            if (w3 > WEPS) { int pos = atomicAdd(&qcnt[qq], 1); if (pos < QCAP) { qwgt[qq][pos] = w3; qkey[qq][pos] = (ky << 7) + kx0 + 3; } }
            float wsum = w0 + w1 + w2 + w3;
            #pragma unroll
            for (int o = 32; o > 0; o >>= 1) wsum += __shfl_xor(wsum, o);
            if ((tid & 63) == 0) redsum[qq][tid >> 6] = wsum;
        }
        __syncthreads();  // (B): queues + sums complete

        #pragma unroll
        for (int qq = 0; qq < QPB; ++qq) {
            float tsum = redsum[qq][0] + redsum[qq][1] + redsum[qq][2] + redsum[qq][3];
            float sc = __expf(SCALE_F * (m[qq] - mn[qq]));   // expf(-inf)=0 first tile
            #pragma unroll
            for (int t = 0; t < 4; ++t) acc[qq][t] *= sc;
            l[qq] = l[qq] * sc + tsum;
            m[qq] = mn[qq];
            int n = qcnt[qq]; if (n > QCAP) n = QCAP;
            for (int e = 0; e < n; ++e) {
                float wv = qwgt[qq][e];
                int kk = qkey[qq][e];
                const float* vb = b2b + (kk >> 7) * WPS + (kk & 127);
                acc[qq][0] += wv * vb[off0];
                acc[qq][1] += wv * vb[off1];
                acc[qq][2] += wv * vb[off2];
                acc[qq][3] += wv * vb[off3];
            }
        }
        __syncthreads();  // (C): protect queues/redbufs before next tile
    }

    #pragma unroll
    for (int qq = 0; qq < QPB; ++qq) {
        int q = (qh << 5) + qw0 + qq;
        float inv = 1.f / l[qq];
        float* zb = Zp + (size_t)(bb * DD) * L1 + q;
        zb[(size_t)tid * L1] = acc[qq][0] * inv;
        zb[(size_t)(tid + 256) * L1] = acc[qq][1] * inv;
        zb[(size_t)(tid + 512) * L1] = acc[qq][2] * inv;
        if (tid < DD - 768) zb[(size_t)(tid + 768) * L1] = acc[qq][3] * inv;
    }
}

// K3: fold (overlap-add gather) + divide by overlap count + 1x1 out conv + residual.
__global__ __launch_bounds__(256) void k_fold(
    const float* __restrict__ bin, const float* __restrict__ ow,
    const float* __restrict__ ob, const float* __restrict__ Zp,
    float* __restrict__ outp)
{
    int p = blockIdx.x * 256 + threadIdx.x;
    if (p >= NB * HH * WW) return;
    int ox = p % WW; int r = p / WW; int oy = r % HH; int bb = r / HH;
    int yp = oy + PAD, xp = ox + PAD;
    int qh0 = (yp - 3) >> 2, qh1 = min(31, yp >> 2);
    int qw0 = (xp - 3) >> 2, qw1 = min(31, xp >> 2);
    float cnt = (float)((qh1 - qh0 + 1) * (qw1 - qw0 + 1));
    float y16[CIT];
    for (int c = 0; c < CIT; ++c) {
        float s = 0.f;
        for (int qhh = qh0; qhh <= qh1; ++qhh) {
            int i = yp - 4 * qhh;
            for (int qww = qw0; qww <= qw1; ++qww) {
                int j = xp - 4 * qww;
                s += Zp[(size_t)(bb * DD + c * 49 + i * 7 + j) * L1 + qhh * 32 + qww];
            }
        }
        y16[c] = s / cnt;
    }
    size_t oidx = ((size_t)(bb * CIN) * HH + oy) * WW + ox;
    for (int co = 0; co < CIN; ++co) {
        float a = ob[co];
        #pragma unroll
        for (int c = 0; c < CIT; ++c) a += ow[co * CIT + c] * y16[c];
        outp[oidx + (size_t)co * HH * WW] = bin[oidx + (size_t)co * HH * WW] + a;
    }
}

extern "C" void kernel_launch(void* const* d_in, const int* in_sizes, int n_in,
                              void* d_out, int out_size, void* d_ws, size_t ws_size,
                              hipStream_t stream) {
    (void)in_sizes; (void)n_in; (void)out_size; (void)ws_size;
    const float* bin = (const float*)d_in[0];
    const float* gw  = (const float*)d_in[1];
    const float* gb  = (const float*)d_in[2];
    const float* tw  = (const float*)d_in[3];
    const float* tb  = (const float*)d_in[4];
    const float* pw  = (const float*)d_in[5];
    const float* pb  = (const float*)d_in[6];
    const float* ow  = (const float*)d_in[7];
    const float* ob  = (const float*)d_in[8];
    float* ws  = (float*)d_ws;
    float* b1p = ws;
    float* b2p = ws + SZPB;
    float* b3p = ws + 2 * (size_t)SZPB;
    float* Zp  = ws + 3 * (size_t)SZPB;   // [NB][DD][L1] fp32
    float* outp = (float*)d_out;

    hipLaunchKernelGGL(k_prep, dim3((NB * HP * WPS + 255) / 256), dim3(256), 0, stream,
                       bin, gw, gb, tw, tb, pw, pb, b1p, b2p, b3p);
    hipLaunchKernelGGL(k_attn, dim3(NB * L1 / QPB), dim3(256), 0, stream,
                       b1p, b2p, b3p, Zp);
    hipLaunchKernelGGL(k_fold, dim3((NB * HH * WW + 255) / 256), dim3(256), 0, stream,
                       bin, ow, ob, Zp, outp);
}

// Round 4
// 353.915 us; speedup vs baseline: 13.3137x; 4.1827x over previous
//
#include <hip/hip_runtime.h>
#include <math.h>

#define NB 4
#define CIN 64
#define CIT 16
#define KS 7
#define PAD 3
#define HH 128
#define WW 128
#define HP 134          // 128 + 2*3
#define WPS 136         // padded row width (px)
#define L1 1024         // 32*32 query patches
#define DD 784          // 16*49
#define SCALE_F 10.0f
#define CAP 56          // candidate capacity per (query, quarter)
#define WSCR 4.0f       // screening window (raw score units); needed: 2.07 + 2*5sigma_bf16(~0.43)

#define PLANE (CIT * HP * WPS)
#define SZPB (NB * PLANE)           // 1,166,336 floats
#define NPIX (HP * WPS)             // 18,224
#define NHWCSZ (NB * NPIX * CIT)    // 1,166,336 shorts

typedef __attribute__((ext_vector_type(4))) float f32x4;
typedef __attribute__((ext_vector_type(8))) short s16x8;
typedef __attribute__((ext_vector_type(4))) unsigned int u32x4;

__device__ __forceinline__ unsigned short f2bf(float f) {
    unsigned u = __float_as_uint(f);
    unsigned r = (u + 0x7FFFu + ((u >> 16) & 1u)) >> 16;   // RNE
    return (unsigned short)r;
}
// monotone float <-> unsigned (for atomicMax on unsigned)
__device__ __forceinline__ unsigned enc_u(float f) {
    unsigned u = __float_as_uint(f);
    return (u & 0x80000000u) ? ~u : (u | 0x80000000u);
}
__device__ __forceinline__ float dec_u(unsigned e) {
    unsigned u = (e & 0x80000000u) ? (e ^ 0x80000000u) : ~e;
    return __uint_as_float(u);
}

// K1: fused 1x1 convs -> fp32 padded CHW planes (b1p,b2p,b3p) + bf16 NHWC planes (b1n,b3n)
__global__ __launch_bounds__(256) void k_prep(
    const float* __restrict__ bin,
    const float* __restrict__ gw, const float* __restrict__ gb,
    const float* __restrict__ tw, const float* __restrict__ tb,
    const float* __restrict__ pw, const float* __restrict__ pb,
    float* __restrict__ b1p, float* __restrict__ b2p, float* __restrict__ b3p,
    unsigned short* __restrict__ b1n, unsigned short* __restrict__ b3n)
{
    int p = blockIdx.x * 256 + threadIdx.x;
    if (p >= NB * NPIX) return;
    int x = p % WPS; int r = p / WPS; int y = r % HP; int bb = r / HP;
    bool inter = (x >= PAD && x < PAD + WW && y >= PAD && y < PAD + HH);
    float v[CIN];
    if (inter) {
        int iy = y - PAD, ix = x - PAD;
        const float* src = bin + ((size_t)(bb * CIN) * HH + iy) * WW + ix;
        #pragma unroll
        for (int ci = 0; ci < CIN; ++ci) v[ci] = src[ci * HH * WW];
    }
    int obase = bb * PLANE + y * WPS + x;
    unsigned short o1[CIT], o3[CIT];
    #pragma unroll
    for (int co = 0; co < CIT; ++co) {
        float a1 = 0.f, a2 = 0.f, a3 = 0.f;
        if (inter) {
            a1 = gb[co]; a2 = tb[co]; a3 = pb[co];
            #pragma unroll
            for (int ci = 0; ci < CIN; ++ci) {
                float vv = v[ci];
                a1 += gw[co * CIN + ci] * vv;
                a2 += tw[co * CIN + ci] * vv;
                a3 += pw[co * CIN + ci] * vv;
            }
        }
        b1p[obase + co * NPIX] = a1;
        b2p[obase + co * NPIX] = a2;
        b3p[obase + co * NPIX] = a3;
        o1[co] = f2bf(a1); o3[co] = f2bf(a3);
    }
    unsigned pk1[8], pk3[8];
    #pragma unroll
    for (int kk = 0; kk < 8; ++kk) {
        pk1[kk] = (unsigned)o1[2 * kk] | ((unsigned)o1[2 * kk + 1] << 16);
        pk3[kk] = (unsigned)o3[2 * kk] | ((unsigned)o3[2 * kk + 1] << 16);
    }
    unsigned short* d1 = b1n + (size_t)p * CIT;
    unsigned short* d3 = b3n + (size_t)p * CIT;
    u32x4 w1a = {pk1[0], pk1[1], pk1[2], pk1[3]}, w1b = {pk1[4], pk1[5], pk1[6], pk1[7]};
    u32x4 w3a = {pk3[0], pk3[1], pk3[2], pk3[3]}, w3b = {pk3[4], pk3[5], pk3[6], pk3[7]};
    *(u32x4*)d1 = w1a; *(u32x4*)(d1 + 8) = w1b;
    *(u32x4*)d3 = w3a; *(u32x4*)(d3 + 8) = w3b;
}

// K2: MFMA bf16 screening, TWO-PASS. Block = (batch, 16 queries, ky-quarter). 512 threads.
// Pass 0: full sweep, per-query max only. Pass 1: re-sweep, push all >= max - WSCR.
__global__ __launch_bounds__(512, 2) void k_screen(
    const unsigned short* __restrict__ b1n, const unsigned short* __restrict__ b3n,
    int* __restrict__ gcnt, uint2* __restrict__ gcand)
{
    int blk = blockIdx.x;           // 1024 = bb(4) x qgroup(64) x qt(4)
    int qt = blk & 3;
    int qgroup = (blk >> 2) & 63;
    int bb = blk >> 8;
    int qstart_ky = qt * 32;
    int tid = threadIdx.x;
    int lane = tid & 63, w = tid >> 6;
    int lanelow = lane & 15;
    int h = (lane >> 5) & 1;        // pixel parity within the K=32 chunk
    int clo = (lane >> 4) & 1;      // channel half

    __shared__ __align__(16) short qlds[16 * 800];          // [q][50 px][16 ch] (px49 zero)
    __shared__ __align__(16) short kring[8 * 134 * 16];     // 8 row slots x 134 px x 16 ch
    __shared__ unsigned qmax[16];
    __shared__ float thrq[16];

    const unsigned short* b1nb = b1n + (size_t)bb * (NPIX * CIT);
    const unsigned short* b3nb = b3n + (size_t)bb * (NPIX * CIT);

    int qlo = qgroup * 16;          // first query of group (within batch)
    int qh = qlo >> 5, qw0 = qlo & 31;
    int qybase = 4 * qh;

    if (tid < 16) {
        qmax[tid] = enc_u(-1e30f);
        gcnt[((bb << 10) + qlo + tid) * 4 + qt] = 0;
    }
    // stage Q: 16 queries x 50 pixels x 32B (pixel 49 = zeros)
    for (int task = tid; task < 800; task += 512) {
        int pp = task % 50, qq = task / 50;
        u32x4 lo = {0, 0, 0, 0}, hi = {0, 0, 0, 0};
        if (pp < 49) {
            int i = pp / 7, j = pp % 7;
            int qx = 4 * (qw0 + qq);
            const unsigned short* src = b1nb + ((size_t)(qybase + i) * WPS + qx + j) * CIT;
            lo = *(const u32x4*)src; hi = *(const u32x4*)(src + 8);
        }
        short* dst = qlds + (qq * 50 + pp) * 16;
        *(u32x4*)dst = lo; *(u32x4*)(dst + 8) = hi;
    }
    // stage K ring prologue: rows qstart..qstart+7 (slot == row & 7)
    for (int task = tid; task < 8 * 268; task += 512) {
        int rr = task / 268, ch = task % 268;
        int row = qstart_ky + rr;
        *(u32x4*)(kring + rr * 2144 + ch * 8) =
            *(const u32x4*)(b3nb + (size_t)row * (WPS * CIT) + ch * 8);
    }
    __syncthreads();

    // B fragments (queries) -> registers, persist across both passes
    s16x8 Breg[25];
    #pragma unroll
    for (int s = 0; s < 25; ++s)
        Breg[s] = *(const s16x8*)(qlds + lanelow * 800 + s * 32 + ((lane >> 4) & 3) * 8);

    int t0 = (w & 3) * 2;
    int abase = (t0 * 16 + lanelow) * 16 + clo * 8;

    for (int pass = 0; pass < 2; ++pass) {
        for (int it = 0; it < 16; ++it) {
            int kyb = qstart_ky + 2 * it;
            // prefetch next 2 rows into regs (written to ring after barrier)
            u32x4 pfA = {0, 0, 0, 0}, pfB = {0, 0, 0, 0};
            bool hasB = (tid < 24);
            if (it < 15) {
                int r1 = (tid >= 268);
                int row1 = kyb + 8 + r1;
                int ch1 = tid - r1 * 268;
                pfA = *(const u32x4*)(b3nb + (size_t)row1 * (WPS * CIT) + ch1 * 8);
                if (hasB) {
                    int ch2 = tid + 512 - 268;
                    pfB = *(const u32x4*)(b3nb + (size_t)(kyb + 9) * (WPS * CIT) + ch2 * 8);
                }
            }
            int kyw = kyb + (w >> 2);
            f32x4 C0 = {0.f, 0.f, 0.f, 0.f}, C1 = {0.f, 0.f, 0.f, 0.f};
            #pragma unroll
            for (int s = 0; s < 25; ++s) {
                const int pe = 2 * s;
                const int po = (2 * s + 1 < 49) ? (2 * s + 1) : 0;  // s=24 odd slot: B is zero
                const int ie = pe / 7, je = pe % 7;
                const int io = po / 7, jo = po % 7;
                int i_h = h ? io : ie;
                int j_h = h ? jo : je;
                int slot = (kyw + i_h) & 7;
                const short* ap = kring + slot * 2144 + j_h * 16 + abase;
                s16x8 a0 = *(const s16x8*)ap;
                s16x8 a1 = *(const s16x8*)(ap + 256);
                C0 = __builtin_amdgcn_mfma_f32_16x16x32_bf16(a0, Breg[s], C0, 0, 0, 0);
                C1 = __builtin_amdgcn_mfma_f32_16x16x32_bf16(a1, Breg[s], C1, 0, 0, 0);
            }
            if (pass == 0) {
                // track per-query max only
                #pragma unroll
                for (int tt = 0; tt < 2; ++tt) {
                    f32x4 C = tt ? C1 : C0;
                    float lm = fmaxf(fmaxf(C[0], C[1]), fmaxf(C[2], C[3]));
                    lm = fmaxf(lm, __shfl_xor(lm, 16));
                    lm = fmaxf(lm, __shfl_xor(lm, 32));
                    if (lane < 16) atomicMax(&qmax[lane], enc_u(lm));
                }
            } else {
                // push candidates with the final threshold
                float thr = thrq[lanelow];
                #pragma unroll
                for (int tt = 0; tt < 2; ++tt) {
                    f32x4 C = tt ? C1 : C0;
                    int t = t0 + tt;
                    #pragma unroll
                    for (int rr = 0; rr < 4; ++rr) {
                        if (C[rr] >= thr) {
                            int kx = t * 16 + ((lane >> 4) << 2) + rr;
                            int key = (kyw << 7) + kx;
                            int idx = ((bb << 10) + qlo + lanelow) * 4 + qt;
                            int pos = atomicAdd(&gcnt[idx], 1);
                            if (pos < CAP)
                                gcand[(size_t)idx * CAP + pos] =
                                    make_uint2(__float_as_uint(C[rr]), (unsigned)key);
                        }
                    }
                }
            }
            __syncthreads();    // all waves done reading ring
            if (it < 15) {
                int r1 = (tid >= 268);
                int row1 = kyb + 8 + r1;
                int ch1 = tid - r1 * 268;
                *(u32x4*)(kring + (row1 & 7) * 2144 + ch1 * 8) = pfA;
                if (hasB)
                    *(u32x4*)(kring + ((kyb + 9) & 7) * 2144 + (tid + 512 - 268) * 8) = pfB;
            }
            __syncthreads();    // new rows visible
        }
        if (pass == 0) {
            if (tid < 16) thrq[tid] = dec_u(qmax[tid]) - WSCR;
            // restage ring for pass 1 (rows qstart..qstart+7)
            for (int task = tid; task < 8 * 268; task += 512) {
                int rr = task / 268, ch = task % 268;
                int row = qstart_ky + rr;
                *(u32x4*)(kring + rr * 2144 + ch * 8) =
                    *(const u32x4*)(b3nb + (size_t)row * (WPS * CIT) + ch * 8);
            }
            __syncthreads();
        }
    }
}

// K3: exact fp32 rescore + softmax + sparse PV. One wave per query.
__global__ __launch_bounds__(256) void k_finalize(
    const float* __restrict__ b1p, const float* __restrict__ b2p,
    const float* __restrict__ b3p, const int* __restrict__ gcnt,
    const uint2* __restrict__ gcand, float* __restrict__ Zp)
{
    int wv = threadIdx.x >> 6;
    int lane = threadIdx.x & 63;
    int gq = blockIdx.x * 4 + wv;
    int bb = gq >> 10, q = gq & 1023;
    int qh = q >> 5, qw = q & 31;
    int qy = qh * 4, qx = qw * 4;

    __shared__ unsigned keys_s[4][4 * CAP];
    __shared__ float scores_s[4][4 * CAP];

    const float* b1b = b1p + (size_t)bb * PLANE;
    const float* b2b = b2p + (size_t)bb * PLANE;
    const float* b3b = b3p + (size_t)bb * PLANE;

    int base = gq * 4;
    int cs[4], off[4];
    #pragma unroll
    for (int t = 0; t < 4; ++t) cs[t] = min(gcnt[base + t], CAP);
    off[0] = 0; off[1] = cs[0]; off[2] = off[1] + cs[1]; off[3] = off[2] + cs[2];
    int n = off[3] + cs[3];
    #pragma unroll
    for (int t = 0; t < 4; ++t)
        for (int e = lane; e < cs[t]; e += 64)
            keys_s[wv][off[t] + e] = gcand[(size_t)(base + t) * CAP + e].y;
    __syncthreads();

    // per-lane d slots and Q patch
    float qreg[13]; int offs[13];
    #pragma unroll
    for (int k = 0; k < 13; ++k) {
        int d = lane + 64 * k;
        if (d < DD) {
            int c = d / 49, rm = d % 49, i = rm / 7, j = rm % 7;
            offs[k] = (c * HP + i) * WPS + j;
            qreg[k] = b1b[offs[k] + qy * WPS + qx];
        } else { offs[k] = 0; qreg[k] = 0.f; }
    }
    // pass 1: exact fp32 scores
    for (int ci = 0; ci < n; ++ci) {
        unsigned key = keys_s[wv][ci];
        int kb = (int)(key >> 7) * WPS + (int)(key & 127);
        float s = 0.f;
        #pragma unroll
        for (int k = 0; k < 13; ++k)
            if (lane + 64 * k < DD) s += qreg[k] * b3b[offs[k] + kb];
        #pragma unroll
        for (int o = 32; o > 0; o >>= 1) s += __shfl_xor(s, o);
        if (lane == 0) scores_s[wv][ci] = s;
    }
    __syncthreads();
    // pass 2: softmax + PV
    float m = -1e30f;
    for (int ci = 0; ci < n; ++ci) m = fmaxf(m, scores_s[wv][ci]);
    float l = 0.f, acc[13];
    #pragma unroll
    for (int k = 0; k < 13; ++k) acc[k] = 0.f;
    for (int ci = 0; ci < n; ++ci) {
        float wgt = __expf(SCALE_F * (scores_s[wv][ci] - m));
        l += wgt;
        unsigned key = keys_s[wv][ci];
        int kb = (int)(key >> 7) * WPS + (int)(key & 127);
        #pragma unroll
        for (int k = 0; k < 13; ++k)
            if (lane + 64 * k < DD) acc[k] += wgt * b2b[offs[k] + kb];
    }
    float inv = (n > 0) ? (1.f / l) : 0.f;
    float* zq = Zp + (size_t)gq * DD;
    #pragma unroll
    for (int k = 0; k < 13; ++k) {
        int d = lane + 64 * k;
        if (d < DD) zq[d] = acc[k] * inv;
    }
}

// K4: fold (overlap-add) + count-divide + 1x1 out conv + residual. Zp layout [gq][d].
__global__ __launch_bounds__(256) void k_fold(
    const float* __restrict__ bin, const float* __restrict__ ow,
    const float* __restrict__ ob, const float* __restrict__ Zp,
    float* __restrict__ outp)
{
    int p = blockIdx.x * 256 + threadIdx.x;
    if (p >= NB * HH * WW) return;
    int ox = p % WW; int r = p / WW; int oy = r % HH; int bb = r / HH;
    int yp = oy + PAD, xp = ox + PAD;
    int qh0 = (yp - 3) >> 2, qh1 = min(31, yp >> 2);
    int qw0 = (xp - 3) >> 2, qw1 = min(31, xp >> 2);
    float cnt = (float)((qh1 - qh0 + 1) * (qw1 - qw0 + 1));
    float y16[CIT];
    for (int c = 0; c < CIT; ++c) {
        float s = 0.f;
        for (int qhh = qh0; qhh <= qh1; ++qhh) {
            int i = yp - 4 * qhh;
            for (int qww = qw0; qww <= qw1; ++qww) {
                int j = xp - 4 * qww;
                s += Zp[(size_t)((bb << 10) + qhh * 32 + qww) * DD + c * 49 + i * 7 + j];
            }
        }
        y16[c] = s / cnt;
    }
    size_t oidx = ((size_t)(bb * CIN) * HH + oy) * WW + ox;
    for (int co = 0; co < CIN; ++co) {
        float a = ob[co];
        #pragma unroll
        for (int c = 0; c < CIT; ++c) a += ow[co * CIT + c] * y16[c];
        outp[oidx + (size_t)co * HH * WW] = bin[oidx + (size_t)co * HH * WW] + a;
    }
}

extern "C" void kernel_launch(void* const* d_in, const int* in_sizes, int n_in,
                              void* d_out, int out_size, void* d_ws, size_t ws_size,
                              hipStream_t stream) {
    (void)in_sizes; (void)n_in; (void)out_size; (void)ws_size;
    const float* bin = (const float*)d_in[0];
    const float* gw  = (const float*)d_in[1];
    const float* gb  = (const float*)d_in[2];
    const float* tw  = (const float*)d_in[3];
    const float* tb  = (const float*)d_in[4];
    const float* pw  = (const float*)d_in[5];
    const float* pb  = (const float*)d_in[6];
    const float* ow  = (const float*)d_in[7];
    const float* ob  = (const float*)d_in[8];

    float* outp = (float*)d_out;
    // d_out scratch (consumed before k_fold writes outp):
    float* b3p = outp;                                        // SZPB floats
    unsigned short* b3n = (unsigned short*)(outp + SZPB);     // NHWCSZ shorts
    unsigned short* b1n = b3n + NHWCSZ;                       // NHWCSZ shorts
    uint2* gcand = (uint2*)(outp + 2 * (size_t)SZPB);         // 4096*4*CAP entries (8B)

    float* ws = (float*)d_ws;
    float* b1p = ws;
    float* b2p = ws + SZPB;
    float* Zp  = ws + 2 * (size_t)SZPB;                       // NB*L1*DD floats
    int* gcnt  = (int*)(ws + 2 * (size_t)SZPB + (size_t)NB * L1 * DD);

    hipLaunchKernelGGL(k_prep, dim3((NB * NPIX + 255) / 256), dim3(256), 0, stream,
                       bin, gw, gb, tw, tb, pw, pb, b1p, b2p, b3p, b1n, b3n);
    hipLaunchKernelGGL(k_screen, dim3(1024), dim3(512), 0, stream,
                       b1n, b3n, gcnt, gcand);
    hipLaunchKernelGGL(k_finalize, dim3(1024), dim3(256), 0, stream,
                       b1p, b2p, b3p, gcnt, gcand, Zp);
    hipLaunchKernelGGL(k_fold, dim3((NB * HH * WW + 255) / 256), dim3(256), 0, stream,
                       bin, ow, ob, Zp, outp);
}